// Round 8
// baseline (309.660 us; speedup 1.0000x reference)
//
#include <hip/hip_runtime.h>
#include <hip/hip_bf16.h>

// Problem constants (fixed by the reference).
#define NNODES 10000
#define NEDGES 160000
#define FIN    2208
#define HDIM   512
#define NCLS   2

#define MPAD   10240     // 80 * 128
#define K1PAD  2240      // 2208 padded to multiple of 64
#define BCAP   128       // per-node edge bucket capacity (max degree ~35 here)

typedef __bf16 bf16x8 __attribute__((ext_vector_type(8)));
typedef float  f32x4  __attribute__((ext_vector_type(4)));
typedef unsigned short u16x8 __attribute__((ext_vector_type(8)));

__device__ inline unsigned short f2bf(float f) {
    union { float f; unsigned int u; } v; v.f = f;
    return (unsigned short)((v.u + 0x7FFFu + ((v.u >> 16) & 1u)) >> 16);
}
__device__ inline float bf2f(unsigned short u) {
    union { unsigned int i; float f; } v; v.i = ((unsigned int)u) << 16; return v.f;
}

// ---------------- dispatch 0: cnt zero (fill atomics need it) ----------------
__global__ void k_zero(int* __restrict__ cnt) {
    int i = blockIdx.x * 256 + threadIdx.x;
    if (i < NNODES) cnt[i] = 0;
}

// ---- dispatch 1: LDS-tiled W transposes + x->bf16 convert + edge fill -------
// (R7-verified: coalesced 64x64 tile transpose through [64][65] LDS.)
#define TRB   408
#define CVTB  10240
__global__ void k_prep_cvt_fill(
    const float* __restrict__ W1, const float* __restrict__ W2,
    const float* __restrict__ W3, unsigned short* __restrict__ W1t,
    unsigned short* __restrict__ W2t, unsigned short* __restrict__ W3t,
    const float* __restrict__ x, unsigned short* __restrict__ xb,
    const int* __restrict__ ei, int* __restrict__ cnt, int* __restrict__ bucket) {
    __shared__ float tl[64][65];
    int b = blockIdx.x;
    int t = threadIdx.x;
    if (b < TRB) {
        const float* Wsrc; unsigned short* Wdst; int kt, nt, Kdim, KP;
        if (b < 280)      { Wsrc = W1; Wdst = W1t; kt = b % 35;        nt = b / 35;        Kdim = FIN;  KP = K1PAD; }
        else if (b < 344) { Wsrc = W2; Wdst = W2t; kt = (b-280) % 8;   nt = (b-280) / 8;   Kdim = HDIM; KP = HDIM;  }
        else              { Wsrc = W3; Wdst = W3t; kt = (b-344) % 8;   nt = (b-344) / 8;   Kdim = HDIM; KP = HDIM;  }
        int wv = t >> 6, ln = t & 63;
        #pragma unroll
        for (int p = 0; p < 16; ++p) {
            int kl = p * 4 + wv;
            int k  = kt * 64 + kl;
            tl[kl][ln] = (k < Kdim) ? Wsrc[(size_t)k * HDIM + nt * 64 + ln] : 0.0f;
        }
        __syncthreads();
        #pragma unroll
        for (int p = 0; p < 16; ++p) {
            int nl = p * 4 + wv;
            Wdst[(size_t)(nt * 64 + nl) * KP + kt * 64 + ln] = f2bf(tl[ln][nl]);
        }
        return;
    }
    if (b < TRB + CVTB) {
        int row = b - TRB;
        unsigned short* orow = xb + (size_t)row * K1PAD;
        u16x8 z = {0, 0, 0, 0, 0, 0, 0, 0};
        if (row >= NNODES) {
            for (int c = t; c < K1PAD / 8; c += 256) *(u16x8*)(orow + c * 8) = z;
            return;
        }
        const float* irow = x + (size_t)row * FIN;
        for (int c = t; c < K1PAD / 8; c += 256) {
            int col = c * 8;
            u16x8 o = z;
            if (col + 8 <= FIN) {
                float4 f0 = *(const float4*)(irow + col);
                float4 f1 = *(const float4*)(irow + col + 4);
                o[0] = f2bf(f0.x); o[1] = f2bf(f0.y); o[2] = f2bf(f0.z); o[3] = f2bf(f0.w);
                o[4] = f2bf(f1.x); o[5] = f2bf(f1.y); o[6] = f2bf(f1.z); o[7] = f2bf(f1.w);
            }
            *(u16x8*)(orow + col) = o;
        }
        return;
    }
    int i = (b - TRB - CVTB) * 256 + t;
    if (i < NEDGES) {
        int src = ei[i];
        int dst = ei[NEDGES + i];
        int pos = atomicAdd(&cnt[dst], 1);
        bucket[dst * BCAP + pos] = src;
    }
}

// -------- bf16 MFMA GEMM: 128x128 tile + double-buffer + counted vmcnt -------
// Merge of two harness-verified components:
//  - 128x128 geometry (R5, passed): halves staging traffic vs 128x64
//    (A re-read 4x not 8x: 550 -> 230 MB for gemm1).
//  - 2-deep dbuf + counted vmcnt (R2, passed): hides the staging drain
//    WITHIN the block — required because 320 blocks = 1.25/CU leaves no
//    co-resident block to cover it (R5's failure mode).
// vmcnt(N): 8 loads per stage (4 A + 4 B per thread); wait tile t's 8 while
// tile t+1's 8 stay in flight -> vmcnt(8). LDS 64 KB (2 x (16+16) KB).
#define BKK 64
#define GB  320          // (10240/128) * (512/128)

__device__ __forceinline__ void gemm_body(
    const unsigned short* __restrict__ A, const unsigned short* __restrict__ Bt,
    unsigned short* __restrict__ C, int M, int K, int l) {
    __shared__ char As[2][128 * BKK * 2] __attribute__((aligned(16)));
    __shared__ char Bs[2][128 * BKK * 2] __attribute__((aligned(16)));
    const int tid  = threadIdx.x;
    const int lane = tid & 63;
    const int w    = tid >> 6;
    const int wm   = w & 1, wn = w >> 1;       // 2x2 wave grid
    const int quad = lane >> 4, lq = lane & 15;

    // XCD-aware swizzle over 320 blocks: l = xcd + 8*(bn4 + 4*s8)
    const int xcd   = l & 7;
    const int q     = l >> 3;                  // 0..39
    const int bn    = (q & 3) * 128;           // 4 col-blocks
    const int strip = (q >> 2) * 8 + xcd;      // 0..79
    const int bm    = strip * 128;

    f32x4 acc[4][4] = {};
    const int nk = K / BKK;                    // 35 (gemm1) or 8 (gemm2/3)

    auto stage = [&](int buf, int k0) {
        #pragma unroll
        for (int i = 0; i < 4; ++i) {
            int c = i * 256 + tid;
            int r = c >> 3;
            int g = (c & 7) ^ (r & 7);
            const char* gpA = (const char*)A + ((size_t)(bm + r) * K + k0) * 2 + (g << 4);
            __builtin_amdgcn_global_load_lds(
                (const __attribute__((address_space(1))) void*)gpA,
                (__attribute__((address_space(3))) void*)(As[buf] + c * 16), 16, 0, 0);
        }
        #pragma unroll
        for (int i = 0; i < 4; ++i) {
            int c = i * 256 + tid;
            int r = c >> 3;
            int g = (c & 7) ^ (r & 7);
            const char* gpB = (const char*)Bt + ((size_t)(bn + r) * K + k0) * 2 + (g << 4);
            __builtin_amdgcn_global_load_lds(
                (const __attribute__((address_space(1))) void*)gpB,
                (__attribute__((address_space(3))) void*)(Bs[buf] + c * 16), 16, 0, 0);
        }
    };

    // prologue: stage tiles 0 and 1 (nk >= 2 always: 8 or 35)
    stage(0, 0);
    stage(1, BKK);
    int cur = 0;

    for (int t = 0; t < nk; ++t) {
        // wait tile t's 8 loads (oldest); leave tile t+1's 8 in flight
        if (t + 1 < nk) {
            asm volatile("s_waitcnt vmcnt(8)" ::: "memory");
        } else {
            asm volatile("s_waitcnt vmcnt(0)" ::: "memory");
        }
        __builtin_amdgcn_s_barrier();

        #pragma unroll
        for (int s = 0; s < 2; ++s) {
            bf16x8 af[4], bfr[4];
            int g = s * 4 + quad;
            #pragma unroll
            for (int i = 0; i < 4; ++i) {
                int r = wm * 64 + i * 16 + lq;
                af[i] = *(const bf16x8*)(As[cur] + r * 128 + ((g ^ (r & 7)) << 4));
            }
            #pragma unroll
            for (int j = 0; j < 4; ++j) {
                int n = wn * 64 + j * 16 + lq;
                bfr[j] = *(const bf16x8*)(Bs[cur] + n * 128 + ((g ^ (n & 7)) << 4));
            }
            #pragma unroll
            for (int i = 0; i < 4; ++i)
                #pragma unroll
                for (int j = 0; j < 4; ++j)
                    acc[i][j] = __builtin_amdgcn_mfma_f32_16x16x32_bf16(
                        af[i], bfr[j], acc[i][j], 0, 0, 0);
        }

        // all waves done reading buf cur before anyone overwrites it
        __builtin_amdgcn_s_barrier();
        if (t + 2 < nk) stage(cur, (t + 2) * BKK);   // t+2 has same parity as t
        cur ^= 1;
    }

    #pragma unroll
    for (int i = 0; i < 4; ++i) {
        #pragma unroll
        for (int p = 0; p < 4; ++p) {
            int r = bm + wm * 64 + i * 16 + quad * 4 + p;
            if (r < M) {
                #pragma unroll
                for (int j = 0; j < 4; ++j) {
                    int col = bn + wn * 64 + j * 16 + lq;
                    C[(size_t)r * HDIM + col] = f2bf(acc[i][j][p]);
                }
            }
        }
    }
}

// ---------------- dispatch 2: GEMM1 (320 blocks) + dinv compute (40) ----------
__global__ __launch_bounds__(256) void k_gemm1_dinv(
    const unsigned short* __restrict__ A, const unsigned short* __restrict__ Bt,
    unsigned short* __restrict__ C, int M, int K,
    const int* __restrict__ cnt, float* __restrict__ dinv) {
    int bx = blockIdx.x;
    if (bx < GB) { gemm_body(A, Bt, C, M, K, bx); return; }
    int i = (bx - GB) * 256 + threadIdx.x;
    if (i < NNODES) dinv[i] = rsqrtf((float)cnt[i] + 1.0f);
}

// ---------------- GEMM (layers 2/3) ----------------
__global__ __launch_bounds__(256) void k_gemm_bf16(
    const unsigned short* __restrict__ A, const unsigned short* __restrict__ Bt,
    unsigned short* __restrict__ C, int M, int K) {
    gemm_body(A, Bt, C, M, K, blockIdx.x);
}

// ---------------- aggregation (layers 1/2): 1 wave per node ----------------
// Measured 13.1 us (R4 telemetry) ~= L3 gather floor. Do not touch.
__global__ void k_agg(const unsigned short* __restrict__ Y, const float* __restrict__ dinv,
                      const int* __restrict__ cnt, const int* __restrict__ bucket,
                      const float* __restrict__ bias, unsigned short* __restrict__ Hb) {
    int w = (blockIdx.x * blockDim.x + threadIdx.x) >> 6;
    int lane = threadIdx.x & 63;
    if (w >= MPAD) return;
    unsigned short* hr = Hb + (size_t)w * HDIM + lane * 8;
    if (w >= NNODES) {
        u16x8 z = {0, 0, 0, 0, 0, 0, 0, 0};
        *(u16x8*)hr = z;
        return;
    }
    float di = dinv[w];
    float sw = di * di;
    u16x8 own = *(const u16x8*)(Y + (size_t)w * HDIM + lane * 8);
    float acc[8];
    #pragma unroll
    for (int t = 0; t < 8; ++t) acc[t] = sw * bf2f(own[t]);

    const int* col = bucket + w * BCAP;
    int deg = cnt[w];
    int e = 0;
    for (; e + 4 <= deg; e += 4) {
        int s0 = col[e + 0], s1 = col[e + 1];
        int s2 = col[e + 2], s3 = col[e + 3];
        float w0 = di * dinv[s0], w1 = di * dinv[s1];
        float w2 = di * dinv[s2], w3 = di * dinv[s3];
        u16x8 v0 = *(const u16x8*)(Y + (size_t)s0 * HDIM + lane * 8);
        u16x8 v1 = *(const u16x8*)(Y + (size_t)s1 * HDIM + lane * 8);
        u16x8 v2 = *(const u16x8*)(Y + (size_t)s2 * HDIM + lane * 8);
        u16x8 v3 = *(const u16x8*)(Y + (size_t)s3 * HDIM + lane * 8);
        #pragma unroll
        for (int t = 0; t < 8; ++t) {
            acc[t] += w0 * bf2f(v0[t]);
            acc[t] += w1 * bf2f(v1[t]);
            acc[t] += w2 * bf2f(v2[t]);
            acc[t] += w3 * bf2f(v3[t]);
        }
    }
    for (; e < deg; ++e) {
        int s = col[e];
        float wg = di * dinv[s];
        u16x8 v = *(const u16x8*)(Y + (size_t)s * HDIM + lane * 8);
        #pragma unroll
        for (int t = 0; t < 8; ++t) acc[t] += wg * bf2f(v[t]);
    }

    float4 b0 = ((const float4*)bias)[lane * 2];
    float4 b1 = ((const float4*)bias)[lane * 2 + 1];
    acc[0] += b0.x; acc[1] += b0.y; acc[2] += b0.z; acc[3] += b0.w;
    acc[4] += b1.x; acc[5] += b1.y; acc[6] += b1.z; acc[7] += b1.w;
    u16x8 o;
    #pragma unroll
    for (int t = 0; t < 8; ++t) o[t] = f2bf(fmaxf(acc[t], 0.0f));
    *(u16x8*)hr = o;
}

// ---------------- agg3 + relu + layer-4 GEMM fused ----------------
__global__ void k_agg_g4(const unsigned short* __restrict__ Y, const float* __restrict__ dinv,
                         const int* __restrict__ cnt, const int* __restrict__ bucket,
                         const float* __restrict__ b3, const float* __restrict__ W4,
                         float* __restrict__ Y4) {
    int w = (blockIdx.x * blockDim.x + threadIdx.x) >> 6;
    int lane = threadIdx.x & 63;
    if (w >= NNODES) return;
    float di = dinv[w];
    float sw = di * di;
    u16x8 own = *(const u16x8*)(Y + (size_t)w * HDIM + lane * 8);
    float acc[8];
    #pragma unroll
    for (int t = 0; t < 8; ++t) acc[t] = sw * bf2f(own[t]);

    const int* col = bucket + w * BCAP;
    int deg = cnt[w];
    int e = 0;
    for (; e + 4 <= deg; e += 4) {
        int s0 = col[e + 0], s1 = col[e + 1];
        int s2 = col[e + 2], s3 = col[e + 3];
        float w0 = di * dinv[s0], w1 = di * dinv[s1];
        float w2 = di * dinv[s2], w3 = di * dinv[s3];
        u16x8 v0 = *(const u16x8*)(Y + (size_t)s0 * HDIM + lane * 8);
        u16x8 v1 = *(const u16x8*)(Y + (size_t)s1 * HDIM + lane * 8);
        u16x8 v2 = *(const u16x8*)(Y + (size_t)s2 * HDIM + lane * 8);
        u16x8 v3 = *(const u16x8*)(Y + (size_t)s3 * HDIM + lane * 8);
        #pragma unroll
        for (int t = 0; t < 8; ++t) {
            acc[t] += w0 * bf2f(v0[t]);
            acc[t] += w1 * bf2f(v1[t]);
            acc[t] += w2 * bf2f(v2[t]);
            acc[t] += w3 * bf2f(v3[t]);
        }
    }
    for (; e < deg; ++e) {
        int s = col[e];
        float wg = di * dinv[s];
        u16x8 v = *(const u16x8*)(Y + (size_t)s * HDIM + lane * 8);
        #pragma unroll
        for (int t = 0; t < 8; ++t) acc[t] += wg * bf2f(v[t]);
    }

    float4 b0 = ((const float4*)b3)[lane * 2];
    float4 b1 = ((const float4*)b3)[lane * 2 + 1];
    acc[0] += b0.x; acc[1] += b0.y; acc[2] += b0.z; acc[3] += b0.w;
    acc[4] += b1.x; acc[5] += b1.y; acc[6] += b1.z; acc[7] += b1.w;
    #pragma unroll
    for (int t = 0; t < 8; ++t) acc[t] = fmaxf(acc[t], 0.0f);

    const float4* wf = (const float4*)W4;
    float4 w0 = wf[lane * 4 + 0];
    float4 w1 = wf[lane * 4 + 1];
    float4 w2 = wf[lane * 4 + 2];
    float4 w3 = wf[lane * 4 + 3];
    float z0 = acc[0]*w0.x + acc[1]*w0.z + acc[2]*w1.x + acc[3]*w1.z
             + acc[4]*w2.x + acc[5]*w2.z + acc[6]*w3.x + acc[7]*w3.z;
    float z1 = acc[0]*w0.y + acc[1]*w0.w + acc[2]*w1.y + acc[3]*w1.w
             + acc[4]*w2.y + acc[5]*w2.w + acc[6]*w3.y + acc[7]*w3.w;
    #pragma unroll
    for (int off = 32; off > 0; off >>= 1) {
        z0 += __shfl_down(z0, off);
        z1 += __shfl_down(z1, off);
    }
    if (lane == 0) {
        Y4[2 * w] = z0;
        Y4[2 * w + 1] = z1;
    }
}

// ---------------- layer-4 aggregation + bias + log_softmax ----------------
__global__ void k_final(const float* __restrict__ Y4, const float* __restrict__ dinv,
                        const int* __restrict__ cnt, const int* __restrict__ bucket,
                        const float* __restrict__ b4, float* __restrict__ out, int n) {
    int i = blockIdx.x * blockDim.x + threadIdx.x;
    if (i >= n) return;
    float di = dinv[i];
    float sw = di * di;
    float z0 = sw * Y4[2 * i];
    float z1 = sw * Y4[2 * i + 1];
    const int* col = bucket + i * BCAP;
    int deg = cnt[i];
    for (int e = 0; e < deg; ++e) {
        int s = col[e];
        float wgt = di * dinv[s];
        z0 += wgt * Y4[2 * s];
        z1 += wgt * Y4[2 * s + 1];
    }
    z0 += b4[0];
    z1 += b4[1];
    float m = fmaxf(z0, z1);
    float l = m + logf(expf(z0 - m) + expf(z1 - m));
    out[2 * i] = z0 - l;
    out[2 * i + 1] = z1 - l;
}

// ---------------- launch ----------------

extern "C" void kernel_launch(void* const* d_in, const int* in_sizes, int n_in,
                              void* d_out, int out_size, void* d_ws, size_t ws_size,
                              hipStream_t stream) {
    const float* x  = (const float*)d_in[0];
    const int*   ei = (const int*)d_in[1];
    const float* W1 = (const float*)d_in[3];
    const float* b1 = (const float*)d_in[4];
    const float* W2 = (const float*)d_in[5];
    const float* b2 = (const float*)d_in[6];
    const float* W3 = (const float*)d_in[7];
    const float* b3 = (const float*)d_in[8];
    const float* W4 = (const float*)d_in[9];
    const float* b4 = (const float*)d_in[10];
    float* out = (float*)d_out;

    char* ws = (char*)d_ws;
    float*          dinv    = (float*)(ws + 0);                  // 40,960
    int*            cnt     = (int*)  (ws + 40960);              // 40,960
    int*            bucket  = (int*)  (ws + 81920);              // 5,120,000
    float*          Y4      = (float*)(ws + 5201920);            // 81,920
    unsigned short* xb      = (unsigned short*)(ws + 5283840);   // 45,875,200
    unsigned short* W1t     = (unsigned short*)(ws + 51159040);  // 2,293,760
    unsigned short* W2t     = (unsigned short*)(ws + 53452800);  // 524,288
    unsigned short* W3t     = (unsigned short*)(ws + 53977088);  // 524,288
    unsigned short* Yb      = (unsigned short*)(ws + 54501376);  // 10,485,760
    unsigned short* Hb      = (unsigned short*)(ws + 64987136);  // 10,485,760
    if (ws_size < 75472896) return;

    const int agrid = (MPAD * 64) / 256;  // one wave per (padded) node

    // d0: cnt zero (tiny; fill atomics in d1 need it)
    k_zero<<<40, 256, 0, stream>>>(cnt);
    // d1: tiled W transposes + x->bf16 convert + edge fill (merged)
    k_prep_cvt_fill<<<TRB + CVTB + 625, 256, 0, stream>>>(
        W1, W2, W3, W1t, W2t, W3t, x, xb, ei, cnt, bucket);
    // d2: layer-1 GEMM (128x128 dbuf tiles, 320 blocks) + dinv compute
    k_gemm1_dinv<<<GB + 40, 256, 0, stream>>>(xb, W1t, Yb, NNODES, K1PAD, cnt, dinv);
    // d3: layer-1 aggregation
    k_agg<<<agrid, 256, 0, stream>>>(Yb, dinv, cnt, bucket, b1, Hb);
    // d4/d5: layer 2
    k_gemm_bf16<<<GB, 256, 0, stream>>>(Hb, W2t, Yb, NNODES, HDIM);
    k_agg<<<agrid, 256, 0, stream>>>(Yb, dinv, cnt, bucket, b2, Hb);
    // d6/d7: layer 3 + fused layer-4 GEMM
    k_gemm_bf16<<<GB, 256, 0, stream>>>(Hb, W3t, Yb, NNODES, HDIM);
    k_agg_g4<<<(NNODES * 64) / 256, 256, 0, stream>>>(Yb, dinv, cnt, bucket, b3, W4, Y4);
    // d8: layer-4 aggregation + log_softmax
    k_final<<<40, 256, 0, stream>>>(Y4, dinv, cnt, bucket, b4, out, NNODES);
}

// Round 9
// 304.716 us; speedup vs baseline: 1.0162x; 1.0162x over previous
//
#include <hip/hip_runtime.h>
#include <hip/hip_bf16.h>

// Problem constants (fixed by the reference).
#define NNODES 10000
#define NEDGES 160000
#define FIN    2208
#define HDIM   512
#define NCLS   2

#define MPAD   10240     // 80 * 128
#define K1PAD  2240      // 2208 padded to multiple of 64
#define BCAP   128       // per-node edge bucket capacity (max degree ~35 here)

typedef __bf16 bf16x8 __attribute__((ext_vector_type(8)));
typedef float  f32x4  __attribute__((ext_vector_type(4)));
typedef unsigned short u16x8 __attribute__((ext_vector_type(8)));

__device__ inline unsigned short f2bf(float f) {
    union { float f; unsigned int u; } v; v.f = f;
    return (unsigned short)((v.u + 0x7FFFu + ((v.u >> 16) & 1u)) >> 16);
}
__device__ inline float bf2f(unsigned short u) {
    union { unsigned int i; float f; } v; v.i = ((unsigned int)u) << 16; return v.f;
}

// ---------------- dispatch 0: cnt zero (fill atomics need it) ----------------
__global__ void k_zero(int* __restrict__ cnt) {
    int i = blockIdx.x * 256 + threadIdx.x;
    if (i < NNODES) cnt[i] = 0;
}

// ---- dispatch 1: LDS-tiled W transposes + x->bf16 convert + edge fill -------
// (R7-verified: coalesced 64x64 tile transpose through [64][65] LDS.)
#define TRB   408
#define CVTB  10240
__global__ void k_prep_cvt_fill(
    const float* __restrict__ W1, const float* __restrict__ W2,
    const float* __restrict__ W3, unsigned short* __restrict__ W1t,
    unsigned short* __restrict__ W2t, unsigned short* __restrict__ W3t,
    const float* __restrict__ x, unsigned short* __restrict__ xb,
    const int* __restrict__ ei, int* __restrict__ cnt, int* __restrict__ bucket) {
    __shared__ float tl[64][65];
    int b = blockIdx.x;
    int t = threadIdx.x;
    if (b < TRB) {
        const float* Wsrc; unsigned short* Wdst; int kt, nt, Kdim, KP;
        if (b < 280)      { Wsrc = W1; Wdst = W1t; kt = b % 35;        nt = b / 35;        Kdim = FIN;  KP = K1PAD; }
        else if (b < 344) { Wsrc = W2; Wdst = W2t; kt = (b-280) % 8;   nt = (b-280) / 8;   Kdim = HDIM; KP = HDIM;  }
        else              { Wsrc = W3; Wdst = W3t; kt = (b-344) % 8;   nt = (b-344) / 8;   Kdim = HDIM; KP = HDIM;  }
        int wv = t >> 6, ln = t & 63;
        #pragma unroll
        for (int p = 0; p < 16; ++p) {
            int kl = p * 4 + wv;
            int k  = kt * 64 + kl;
            tl[kl][ln] = (k < Kdim) ? Wsrc[(size_t)k * HDIM + nt * 64 + ln] : 0.0f;
        }
        __syncthreads();
        #pragma unroll
        for (int p = 0; p < 16; ++p) {
            int nl = p * 4 + wv;
            Wdst[(size_t)(nt * 64 + nl) * KP + kt * 64 + ln] = f2bf(tl[ln][nl]);
        }
        return;
    }
    if (b < TRB + CVTB) {
        int row = b - TRB;
        unsigned short* orow = xb + (size_t)row * K1PAD;
        u16x8 z = {0, 0, 0, 0, 0, 0, 0, 0};
        if (row >= NNODES) {
            for (int c = t; c < K1PAD / 8; c += 256) *(u16x8*)(orow + c * 8) = z;
            return;
        }
        const float* irow = x + (size_t)row * FIN;
        for (int c = t; c < K1PAD / 8; c += 256) {
            int col = c * 8;
            u16x8 o = z;
            if (col + 8 <= FIN) {
                float4 f0 = *(const float4*)(irow + col);
                float4 f1 = *(const float4*)(irow + col + 4);
                o[0] = f2bf(f0.x); o[1] = f2bf(f0.y); o[2] = f2bf(f0.z); o[3] = f2bf(f0.w);
                o[4] = f2bf(f1.x); o[5] = f2bf(f1.y); o[6] = f2bf(f1.z); o[7] = f2bf(f1.w);
            }
            *(u16x8*)(orow + col) = o;
        }
        return;
    }
    int i = (b - TRB - CVTB) * 256 + t;
    if (i < NEDGES) {
        int src = ei[i];
        int dst = ei[NEDGES + i];
        int pos = atomicAdd(&cnt[dst], 1);
        bucket[dst * BCAP + pos] = src;
    }
}

// ---------------- bf16 MFMA GEMM body: verified 128x64 tile ----------------
// Final structure after 4 experiments: 128x64 @ 640 blocks (2.5/CU) beats
// 128x128 @ 320 (R5: -13us), 128x128+dbuf @ 320 (R8: -7.5us), and dbuf@640
// (R2: null). TLP from co-resident blocks hides the staging drain better
// than any within-block pipelining at this problem size.
#define BKK 64
#define GG1 640

__device__ __forceinline__ void gemm_body(
    const unsigned short* __restrict__ A, const unsigned short* __restrict__ Bt,
    unsigned short* __restrict__ C, int M, int K, int l) {
    __shared__ char As[128 * BKK * 2] __attribute__((aligned(16)));
    __shared__ char Bs[64 * BKK * 2]  __attribute__((aligned(16)));
    const int tid  = threadIdx.x;
    const int lane = tid & 63;
    const int w    = tid >> 6;
    const int wm   = w & 1, wn = w >> 1;
    const int quad = lane >> 4, lq = lane & 15;

    const int xcd   = l & 7;
    const int q     = l >> 3;
    const int strip = (q >> 3) * 8 + xcd;
    const int bm    = strip * 128;
    const int bn    = (q & 7) * 64;

    f32x4 acc[4][2] = {};

    for (int k0 = 0; k0 < K; k0 += BKK) {
        #pragma unroll
        for (int i = 0; i < 4; ++i) {
            int c = i * 256 + tid;
            int r = c >> 3;
            int g = (c & 7) ^ (r & 7);
            const char* gpA = (const char*)A + ((size_t)(bm + r) * K + k0) * 2 + (g << 4);
            __builtin_amdgcn_global_load_lds(
                (const __attribute__((address_space(1))) void*)gpA,
                (__attribute__((address_space(3))) void*)(As + c * 16), 16, 0, 0);
        }
        #pragma unroll
        for (int i = 0; i < 2; ++i) {
            int c = i * 256 + tid;
            int r = c >> 3;
            int g = (c & 7) ^ (r & 7);
            const char* gpB = (const char*)Bt + ((size_t)(bn + r) * K + k0) * 2 + (g << 4);
            __builtin_amdgcn_global_load_lds(
                (const __attribute__((address_space(1))) void*)gpB,
                (__attribute__((address_space(3))) void*)(Bs + c * 16), 16, 0, 0);
        }
        __syncthreads();

        #pragma unroll
        for (int s = 0; s < 2; ++s) {
            bf16x8 af[4], bfr[2];
            int g = s * 4 + quad;
            #pragma unroll
            for (int i = 0; i < 4; ++i) {
                int r = wm * 64 + i * 16 + lq;
                af[i] = *(const bf16x8*)(As + r * 128 + ((g ^ (r & 7)) << 4));
            }
            #pragma unroll
            for (int j = 0; j < 2; ++j) {
                int n = wn * 32 + j * 16 + lq;
                bfr[j] = *(const bf16x8*)(Bs + n * 128 + ((g ^ (n & 7)) << 4));
            }
            #pragma unroll
            for (int i = 0; i < 4; ++i)
                #pragma unroll
                for (int j = 0; j < 2; ++j)
                    acc[i][j] = __builtin_amdgcn_mfma_f32_16x16x32_bf16(
                        af[i], bfr[j], acc[i][j], 0, 0, 0);
        }
        __syncthreads();
    }

    #pragma unroll
    for (int i = 0; i < 4; ++i) {
        #pragma unroll
        for (int p = 0; p < 4; ++p) {
            int r = bm + wm * 64 + i * 16 + quad * 4 + p;
            if (r < M) {
                #pragma unroll
                for (int j = 0; j < 2; ++j) {
                    int col = bn + wn * 32 + j * 16 + lq;
                    C[(size_t)r * HDIM + col] = f2bf(acc[i][j][p]);
                }
            }
        }
    }
}

// ---------------- dispatch 2: GEMM1 (640 blocks) + dinv compute (40) ----------
__global__ __launch_bounds__(256) void k_gemm1_dinv(
    const unsigned short* __restrict__ A, const unsigned short* __restrict__ Bt,
    unsigned short* __restrict__ C, int M, int K,
    const int* __restrict__ cnt, float* __restrict__ dinv) {
    int bx = blockIdx.x;
    if (bx < GG1) { gemm_body(A, Bt, C, M, K, bx); return; }
    int i = (bx - GG1) * 256 + threadIdx.x;
    if (i < NNODES) dinv[i] = rsqrtf((float)cnt[i] + 1.0f);
}

// ---------------- GEMM (layers 2/3) ----------------
__global__ __launch_bounds__(256) void k_gemm_bf16(
    const unsigned short* __restrict__ A, const unsigned short* __restrict__ Bt,
    unsigned short* __restrict__ C, int M, int K) {
    gemm_body(A, Bt, C, M, K, blockIdx.x);
}

// ---------------- aggregation (layers 1/2): 1 wave per node ----------------
// Measured 13.1 us (R4 telemetry) ~= L3 gather floor. Do not touch.
__global__ void k_agg(const unsigned short* __restrict__ Y, const float* __restrict__ dinv,
                      const int* __restrict__ cnt, const int* __restrict__ bucket,
                      const float* __restrict__ bias, unsigned short* __restrict__ Hb) {
    int w = (blockIdx.x * blockDim.x + threadIdx.x) >> 6;
    int lane = threadIdx.x & 63;
    if (w >= MPAD) return;
    unsigned short* hr = Hb + (size_t)w * HDIM + lane * 8;
    if (w >= NNODES) {
        u16x8 z = {0, 0, 0, 0, 0, 0, 0, 0};
        *(u16x8*)hr = z;
        return;
    }
    float di = dinv[w];
    float sw = di * di;
    u16x8 own = *(const u16x8*)(Y + (size_t)w * HDIM + lane * 8);
    float acc[8];
    #pragma unroll
    for (int t = 0; t < 8; ++t) acc[t] = sw * bf2f(own[t]);

    const int* col = bucket + w * BCAP;
    int deg = cnt[w];
    int e = 0;
    for (; e + 4 <= deg; e += 4) {
        int s0 = col[e + 0], s1 = col[e + 1];
        int s2 = col[e + 2], s3 = col[e + 3];
        float w0 = di * dinv[s0], w1 = di * dinv[s1];
        float w2 = di * dinv[s2], w3 = di * dinv[s3];
        u16x8 v0 = *(const u16x8*)(Y + (size_t)s0 * HDIM + lane * 8);
        u16x8 v1 = *(const u16x8*)(Y + (size_t)s1 * HDIM + lane * 8);
        u16x8 v2 = *(const u16x8*)(Y + (size_t)s2 * HDIM + lane * 8);
        u16x8 v3 = *(const u16x8*)(Y + (size_t)s3 * HDIM + lane * 8);
        #pragma unroll
        for (int t = 0; t < 8; ++t) {
            acc[t] += w0 * bf2f(v0[t]);
            acc[t] += w1 * bf2f(v1[t]);
            acc[t] += w2 * bf2f(v2[t]);
            acc[t] += w3 * bf2f(v3[t]);
        }
    }
    for (; e < deg; ++e) {
        int s = col[e];
        float wg = di * dinv[s];
        u16x8 v = *(const u16x8*)(Y + (size_t)s * HDIM + lane * 8);
        #pragma unroll
        for (int t = 0; t < 8; ++t) acc[t] += wg * bf2f(v[t]);
    }

    float4 b0 = ((const float4*)bias)[lane * 2];
    float4 b1 = ((const float4*)bias)[lane * 2 + 1];
    acc[0] += b0.x; acc[1] += b0.y; acc[2] += b0.z; acc[3] += b0.w;
    acc[4] += b1.x; acc[5] += b1.y; acc[6] += b1.z; acc[7] += b1.w;
    u16x8 o;
    #pragma unroll
    for (int t = 0; t < 8; ++t) o[t] = f2bf(fmaxf(acc[t], 0.0f));
    *(u16x8*)hr = o;
}

// ---------------- agg3 + relu + layer-4 GEMM fused ----------------
__global__ void k_agg_g4(const unsigned short* __restrict__ Y, const float* __restrict__ dinv,
                         const int* __restrict__ cnt, const int* __restrict__ bucket,
                         const float* __restrict__ b3, const float* __restrict__ W4,
                         float* __restrict__ Y4) {
    int w = (blockIdx.x * blockDim.x + threadIdx.x) >> 6;
    int lane = threadIdx.x & 63;
    if (w >= NNODES) return;
    float di = dinv[w];
    float sw = di * di;
    u16x8 own = *(const u16x8*)(Y + (size_t)w * HDIM + lane * 8);
    float acc[8];
    #pragma unroll
    for (int t = 0; t < 8; ++t) acc[t] = sw * bf2f(own[t]);

    const int* col = bucket + w * BCAP;
    int deg = cnt[w];
    int e = 0;
    for (; e + 4 <= deg; e += 4) {
        int s0 = col[e + 0], s1 = col[e + 1];
        int s2 = col[e + 2], s3 = col[e + 3];
        float w0 = di * dinv[s0], w1 = di * dinv[s1];
        float w2 = di * dinv[s2], w3 = di * dinv[s3];
        u16x8 v0 = *(const u16x8*)(Y + (size_t)s0 * HDIM + lane * 8);
        u16x8 v1 = *(const u16x8*)(Y + (size_t)s1 * HDIM + lane * 8);
        u16x8 v2 = *(const u16x8*)(Y + (size_t)s2 * HDIM + lane * 8);
        u16x8 v3 = *(const u16x8*)(Y + (size_t)s3 * HDIM + lane * 8);
        #pragma unroll
        for (int t = 0; t < 8; ++t) {
            acc[t] += w0 * bf2f(v0[t]);
            acc[t] += w1 * bf2f(v1[t]);
            acc[t] += w2 * bf2f(v2[t]);
            acc[t] += w3 * bf2f(v3[t]);
        }
    }
    for (; e < deg; ++e) {
        int s = col[e];
        float wg = di * dinv[s];
        u16x8 v = *(const u16x8*)(Y + (size_t)s * HDIM + lane * 8);
        #pragma unroll
        for (int t = 0; t < 8; ++t) acc[t] += wg * bf2f(v[t]);
    }

    float4 b0 = ((const float4*)b3)[lane * 2];
    float4 b1 = ((const float4*)b3)[lane * 2 + 1];
    acc[0] += b0.x; acc[1] += b0.y; acc[2] += b0.z; acc[3] += b0.w;
    acc[4] += b1.x; acc[5] += b1.y; acc[6] += b1.z; acc[7] += b1.w;
    #pragma unroll
    for (int t = 0; t < 8; ++t) acc[t] = fmaxf(acc[t], 0.0f);

    const float4* wf = (const float4*)W4;
    float4 w0 = wf[lane * 4 + 0];
    float4 w1 = wf[lane * 4 + 1];
    float4 w2 = wf[lane * 4 + 2];
    float4 w3 = wf[lane * 4 + 3];
    float z0 = acc[0]*w0.x + acc[1]*w0.z + acc[2]*w1.x + acc[3]*w1.z
             + acc[4]*w2.x + acc[5]*w2.z + acc[6]*w3.x + acc[7]*w3.z;
    float z1 = acc[0]*w0.y + acc[1]*w0.w + acc[2]*w1.y + acc[3]*w1.w
             + acc[4]*w2.y + acc[5]*w2.w + acc[6]*w3.y + acc[7]*w3.w;
    #pragma unroll
    for (int off = 32; off > 0; off >>= 1) {
        z0 += __shfl_down(z0, off);
        z1 += __shfl_down(z1, off);
    }
    if (lane == 0) {
        Y4[2 * w] = z0;
        Y4[2 * w + 1] = z1;
    }
}

// ---------------- layer-4 aggregation + bias + log_softmax ----------------
__global__ void k_final(const float* __restrict__ Y4, const float* __restrict__ dinv,
                        const int* __restrict__ cnt, const int* __restrict__ bucket,
                        const float* __restrict__ b4, float* __restrict__ out, int n) {
    int i = blockIdx.x * blockDim.x + threadIdx.x;
    if (i >= n) return;
    float di = dinv[i];
    float sw = di * di;
    float z0 = sw * Y4[2 * i];
    float z1 = sw * Y4[2 * i + 1];
    const int* col = bucket + i * BCAP;
    int deg = cnt[i];
    for (int e = 0; e < deg; ++e) {
        int s = col[e];
        float wgt = di * dinv[s];
        z0 += wgt * Y4[2 * s];
        z1 += wgt * Y4[2 * s + 1];
    }
    z0 += b4[0];
    z1 += b4[1];
    float m = fmaxf(z0, z1);
    float l = m + logf(expf(z0 - m) + expf(z1 - m));
    out[2 * i] = z0 - l;
    out[2 * i + 1] = z1 - l;
}

// ---------------- launch ----------------

extern "C" void kernel_launch(void* const* d_in, const int* in_sizes, int n_in,
                              void* d_out, int out_size, void* d_ws, size_t ws_size,
                              hipStream_t stream) {
    const float* x  = (const float*)d_in[0];
    const int*   ei = (const int*)d_in[1];
    const float* W1 = (const float*)d_in[3];
    const float* b1 = (const float*)d_in[4];
    const float* W2 = (const float*)d_in[5];
    const float* b2 = (const float*)d_in[6];
    const float* W3 = (const float*)d_in[7];
    const float* b3 = (const float*)d_in[8];
    const float* W4 = (const float*)d_in[9];
    const float* b4 = (const float*)d_in[10];
    float* out = (float*)d_out;

    char* ws = (char*)d_ws;
    float*          dinv    = (float*)(ws + 0);                  // 40,960
    int*            cnt     = (int*)  (ws + 40960);              // 40,960
    int*            bucket  = (int*)  (ws + 81920);              // 5,120,000
    float*          Y4      = (float*)(ws + 5201920);            // 81,920
    unsigned short* xb      = (unsigned short*)(ws + 5283840);   // 45,875,200
    unsigned short* W1t     = (unsigned short*)(ws + 51159040);  // 2,293,760
    unsigned short* W2t     = (unsigned short*)(ws + 53452800);  // 524,288
    unsigned short* W3t     = (unsigned short*)(ws + 53977088);  // 524,288
    unsigned short* Yb      = (unsigned short*)(ws + 54501376);  // 10,485,760
    unsigned short* Hb      = (unsigned short*)(ws + 64987136);  // 10,485,760
    if (ws_size < 75472896) return;

    const int agrid = (MPAD * 64) / 256;  // one wave per (padded) node

    // d0: cnt zero (tiny; fill atomics in d1 need it)
    k_zero<<<40, 256, 0, stream>>>(cnt);
    // d1: tiled W transposes + x->bf16 convert + edge fill (merged)
    k_prep_cvt_fill<<<TRB + CVTB + 625, 256, 0, stream>>>(
        W1, W2, W3, W1t, W2t, W3t, x, xb, ei, cnt, bucket);
    // d2: layer-1 GEMM (128x64 tiles, 640 blocks) + dinv compute
    k_gemm1_dinv<<<GG1 + 40, 256, 0, stream>>>(xb, W1t, Yb, NNODES, K1PAD, cnt, dinv);
    // d3: layer-1 aggregation
    k_agg<<<agrid, 256, 0, stream>>>(Yb, dinv, cnt, bucket, b1, Hb);
    // d4/d5: layer 2
    k_gemm_bf16<<<GG1, 256, 0, stream>>>(Hb, W2t, Yb, NNODES, HDIM);
    k_agg<<<agrid, 256, 0, stream>>>(Yb, dinv, cnt, bucket, b2, Hb);
    // d6/d7: layer 3 + fused layer-4 GEMM
    k_gemm_bf16<<<GG1, 256, 0, stream>>>(Hb, W3t, Yb, NNODES, HDIM);
    k_agg_g4<<<(NNODES * 64) / 256, 256, 0, stream>>>(Yb, dinv, cnt, bucket, b3, W4, Y4);
    // d8: layer-4 aggregation + log_softmax
    k_final<<<40, 256, 0, stream>>>(Y4, dinv, cnt, bucket, b4, out, NNODES);
}